// Round 5
// 1081.870 us; speedup vs baseline: 3.0573x; 3.0573x over previous
//
#include <hip/hip_runtime.h>

typedef unsigned short ushort_t;
typedef unsigned int uint_t;

typedef short short8 __attribute__((ext_vector_type(8)));
typedef __bf16 bf16x8 __attribute__((ext_vector_type(8)));
typedef float fx4 __attribute__((ext_vector_type(4)));
typedef float fx16 __attribute__((ext_vector_type(16)));

// ---------- bf16 helpers ----------
__device__ __forceinline__ float bf2f(ushort_t u) {
    return __uint_as_float(((uint_t)u) << 16);
}
__device__ __forceinline__ ushort_t f2bf(float f) {
    uint_t x = __float_as_uint(f);
    return (ushort_t)((x + 0x7fffu + ((x >> 16) & 1u)) >> 16);  // RNE
}
// pack two floats to bf16 pair (lo | hi<<16), pure C
__device__ __forceinline__ uint_t pkbf(float lo, float hi) {
    return (uint_t)f2bf(lo) | ((uint_t)f2bf(hi) << 16);
}
// dtype-dispatched load: mode==1 -> buffer holds bf16, mode==0 -> fp32
__device__ __forceinline__ float ldx(const void* p, long i, int mode) {
    return mode ? bf2f(((const ushort_t*)p)[i]) : ((const float*)p)[i];
}

// ---------- workspace layout (float offsets) ----------
// wfrag: [layer4][chf2][kk3][m3][lane64][j8] bf16  = 36864 u16 = 18432 floats
#define OFF_WF   0
#define OFF_W1F  18432   // [ct3][lane64][j8] bf16 = 1536 u16 = 768 floats
#define OFF_BIAS 19200   // [5][48] f32
#define OFF_MODE 19456
#define OFF_PART 19520   // 8192*48 f32
#define OFF_Z    412736  // 128*640 f32

// ---------- conv LDS layout (byte offsets), static shared ----------
#define INROWS 258
#define O_IN   0                       // [258][16B]  input chunk (single buf)
#define O_L1   4128                    // [129][128B] (row0 = halo)
#define O_L2   20640                   // [65][128B]
#define O_L3   28960                   // [257][128B]
#define L_TOTAL 61856                  // <= 64 KiB, 2 blocks/CU
#define O_L4   O_L1                    // L4 overlays L1 (dead by then)
#define O_SUM  O_L2                    // float [2][48] for L5 reduce

// swizzled byte address inside a 64-bf16-pitch activation buffer
__device__ __forceinline__ int swz(int r, int blk) {
    return (r << 7) + ((blk ^ ((r >> 1) & 7)) << 4);
}
__device__ __forceinline__ fx4 mfma16(fx4 acc, short8 a, short8 b) {
    return __builtin_amdgcn_mfma_f32_16x16x32_bf16(
        __builtin_bit_cast(bf16x8, a), __builtin_bit_cast(bf16x8, b), acc, 0, 0, 0);
}
__device__ __forceinline__ fx16 mfma32(fx16 acc, short8 a, short8 b) {
    return __builtin_amdgcn_mfma_f32_32x32x16_bf16(
        __builtin_bit_cast(bf16x8, a), __builtin_bit_cast(bf16x8, b), acc, 0, 0, 0);
}
__device__ __forceinline__ fx16 zero16() {
    fx16 z;
    #pragma unroll
    for (int i = 0; i < 16; i++) z[i] = 0.f;
    return z;
}
// bias-init for a 32x32 C tile: row = 8q + 4h + i (+32*chf)
__device__ __forceinline__ fx16 bias16(const float* bp, int chf, int h) {
    fx16 r;
    #pragma unroll
    for (int q = 0; q < 4; q++) {
        fx4 b4 = *(const fx4*)(bp + 32 * chf + 8 * q + 4 * h);
        r[4 * q + 0] = b4.x; r[4 * q + 1] = b4.y;
        r[4 * q + 2] = b4.z; r[4 * q + 3] = b4.w;
    }
    return r;
}
// ReLU + bf16-pack + store a 32x32 C tile (transposed: act[col][co]) into buf
__device__ __forceinline__ void store32(char* base, int r, int chf, int h, fx16 acc) {
    const int off = h << 3;
    const int nq = chf ? 2 : 4;  // skip co>=48
    #pragma unroll
    for (int q = 0; q < 4; q++) {
        if (q < nq) {
            uint2 p;
            p.x = pkbf(fmaxf(acc[4 * q + 0], 0.f), fmaxf(acc[4 * q + 1], 0.f));
            p.y = pkbf(fmaxf(acc[4 * q + 2], 0.f), fmaxf(acc[4 * q + 3], 0.f));
            *(uint2*)(base + swz(r, q + 4 * chf) + off) = p;
        }
    }
}

// ---------------------------------------------------------------------------
// Prep: sniff input dtype, then pack conv weights into per-lane MFMA A-frags
// (bf16) + f32 biases [5][48].
// ---------------------------------------------------------------------------
__global__ __launch_bounds__(256) void prep_kernel(
    const void* sig, const void* w0, const void* b0, const void* w1, const void* b1,
    const void* w2, const void* b2, const void* w3, const void* b3,
    const void* w4, const void* b4, float* wt, int* mode_out)
{
    __shared__ int cnt[4];
    __shared__ int smode;
    const int tid = threadIdx.x;
    {
        const uint_t* su = (const uint_t*)sig;
        int local = 0;
        for (int i = tid; i < 4096; i += 256) {
            uint_t e = (su[i] >> 7) & 0xFFu;
            local += (e >= 112u && e <= 144u) ? 1 : 0;
        }
        for (int off = 32; off > 0; off >>= 1) local += __shfl_down(local, off, 64);
        if ((tid & 63) == 0) cnt[tid >> 6] = local;
        __syncthreads();
        if (tid == 0) {
            int t = cnt[0] + cnt[1] + cnt[2] + cnt[3];
            int m = (t >= 2048) ? 1 : 0;
            smode = m;
            *mode_out = m;
        }
        __syncthreads();
    }
    const int mode = smode;

    // layers 2..5 A-frags: co = 32*chf + (l&31), ci = 16*m + 8*(l>>5) + j
    ushort_t* wfu = (ushort_t*)wt;
    const void* wsrc[4] = {w1, w2, w3, w4};
    for (int idx = tid; idx < 36864; idx += 256) {
        int j = idx & 7, l = (idx >> 3) & 63;
        int F = idx >> 9;                 // (layer*2+chf)*9 + kk*3 + m
        int m = F % 3, kk = (F / 3) % 3, chf = (F / 9) & 1, layer = F / 18;
        int co = 32 * chf + (l & 31);
        int ci = 16 * m + 8 * (l >> 5) + j;
        float v = (co < 45 && ci < 45) ? ldx(wsrc[layer], co * 135 + ci * 3 + kk, mode) : 0.f;
        wfu[idx] = f2bf(v);
    }
    // L1 A-frags (16x16x32, kk-major im2col: k = 8*kk + ci)
    ushort_t* w1u = (ushort_t*)(wt + OFF_W1F);
    for (int idx = tid; idx < 1536; idx += 256) {
        int j = idx & 7, l = (idx >> 3) & 63, ct = idx >> 9;
        int g = l >> 4, co = 16 * ct + (l & 15);
        float v = (co < 45 && g < 3 && j < 4) ? ldx(w0, co * 12 + j * 3 + g, mode) : 0.f;
        w1u[idx] = f2bf(v);
    }
    // biases [5][48]
    float* bias = wt + OFF_BIAS;
    const void* bsrc[5] = {b0, b1, b2, b3, b4};
    for (int idx = tid; idx < 240; idx += 256) {
        int l = idx / 48, co = idx % 48;
        bias[idx] = (co < 45) ? ldx(bsrc[l], co, mode) : 0.f;
    }
}

// ---------------------------------------------------------------------------
// Fused 5-layer conv encoder, MFMA version. One block per sample, 4 waves.
// Activations transposed in LDS: act[x][co] bf16, 64-elem pitch, XOR-swizzled
// 16B blocks. Layers 2-5: 32x32x16 bf16 MFMA, kk-decomposed (K=48 per tap).
// 8 chunks of 128 L1-cols; carried halo = LDS row 0 of each buffer.
// ---------------------------------------------------------------------------
__global__ __launch_bounds__(256, 2) void conv_kernel(
    const void* sig, const float* wt, const int* mode_p, float* partial)
{
    __shared__ __align__(16) char lds[L_TOTAL];
    const int tid  = threadIdx.x;
    const int lane = tid & 63;
    const int w    = __builtin_amdgcn_readfirstlane(tid >> 6);
    const int s    = blockIdx.x;
    const int mode = *mode_p;
    const long sbase = (long)s * 8192;

    const short8* wf   = (const short8*)wt;
    const short8* w1f  = (const short8*)(wt + OFF_W1F);
    const float*  bias = wt + OFF_BIAS;

    const int h   = lane >> 5;   // 0/1 : K-half for 32x32 frags
    const int l31 = lane & 31;
    const int l15 = lane & 15;
    const int g   = lane >> 4;   // 0..3 : kk for L1 frags
    const int chf = w & 1;       // co-half for layers 2..5

    // resident A-fragments: L1 (3 co-tiles), L2 + L3 (9 frags each, own co-half)
    short8 a1[3], aL2[9], aL3[9];
    #pragma unroll
    for (int ct = 0; ct < 3; ct++) a1[ct] = w1f[ct * 64 + lane];
    #pragma unroll
    for (int f = 0; f < 9; f++) aL2[f] = wf[(chf * 9 + f) * 64 + lane];
    {
        const int c3 = (w < 2) ? w : chf;
        #pragma unroll
        for (int f = 0; f < 9; f++) aL3[f] = wf[((2 + c3) * 9 + f) * 64 + lane];
    }
    fx4 b1v[3];
    #pragma unroll
    for (int ct = 0; ct < 3; ct++) b1v[ct] = *(const fx4*)(bias + 16 * ct + 4 * g);

    char* inb = lds + O_IN;
    char* l1b = lds + O_L1;
    char* l2b = lds + O_L2;
    char* l3b = lds + O_L3;

    // ---- prologue: stage input chunk 0 (transposed, bf16) + zero halo rows
    {
        for (int ri = tid; ri < INROWS; ri += 256) {
            int x = ri - 1;
            uint_t p0 = 0, p1 = 0;
            if (x >= 0 && x < 2048) {
                float f0 = ldx(sig, sbase + x, mode);
                float f1 = ldx(sig, sbase + 2048 + x, mode);
                float f2 = ldx(sig, sbase + 4096 + x, mode);
                float f3 = ldx(sig, sbase + 6144 + x, mode);
                p0 = pkbf(f0, f1); p1 = pkbf(f2, f3);
            }
            uint4 vv; vv.x = p0; vv.y = p1; vv.z = 0; vv.w = 0;
            *(uint4*)(inb + ri * 16) = vv;
        }
        if (tid < 32) {
            *(uint_t*)(l1b + tid * 4) = 0;
            *(uint_t*)(l2b + tid * 4) = 0;
            *(uint_t*)(l3b + tid * 4) = 0;
        }
    }
    __syncthreads();

    for (int k = 0; k < 8; k++) {
        // ---- P1: L1 over 128 cols (8 tiles of 16; wave -> tiles {w, w+4})
        //         + carry L2 halo (row 64 -> row 0) for this chunk's L3
        if (k > 0 && tid < 32)
            *(uint_t*)(l2b + tid * 4) = *(const uint_t*)(l2b + 64 * 128 + tid * 4);
        #pragma unroll
        for (int u = 0; u < 2; u++) {
            const int cl = (w + 4 * u) * 16 + l15;
            short8 bfrag = *(const short8*)(inb + (2 * cl + g) * 16);
            fx4 c0 = mfma16(b1v[0], a1[0], bfrag);
            fx4 c1 = mfma16(b1v[1], a1[1], bfrag);
            fx4 c2 = mfma16(b1v[2], a1[2], bfrag);
            const int r = 1 + cl;
            const int off = (g & 1) << 3;
            const int bq = g >> 1;
            uint2 p;
            p.x = pkbf(fmaxf(c0.x, 0.f), fmaxf(c0.y, 0.f));
            p.y = pkbf(fmaxf(c0.z, 0.f), fmaxf(c0.w, 0.f));
            *(uint2*)(l1b + swz(r, 0 + bq) + off) = p;
            p.x = pkbf(fmaxf(c1.x, 0.f), fmaxf(c1.y, 0.f));
            p.y = pkbf(fmaxf(c1.z, 0.f), fmaxf(c1.w, 0.f));
            *(uint2*)(l1b + swz(r, 2 + bq) + off) = p;
            p.x = pkbf(fmaxf(c2.x, 0.f), fmaxf(c2.y, 0.f));
            p.y = pkbf(fmaxf(c2.z, 0.f), fmaxf(c2.w, 0.f));
            *(uint2*)(l1b + swz(r, 4 + bq) + off) = p;
        }
        __syncthreads();

        // ---- P2: L2 over 64 cols (wave -> col-tile w>>1, co-half w&1)
        {
            const int cl = (w >> 1) * 32 + l31;
            const int rb = 2 * cl;
            fx16 s0 = bias16(bias + 48, chf, h);
            fx16 s1 = zero16(), s2 = zero16();
            #pragma unroll
            for (int m = 0; m < 3; m++) {
                short8 bA = *(const short8*)(l1b + swz(rb + 0, 2 * m + h));
                short8 bB = *(const short8*)(l1b + swz(rb + 1, 2 * m + h));
                short8 bC = *(const short8*)(l1b + swz(rb + 2, 2 * m + h));
                s0 = mfma32(s0, aL2[0 + m], bA);
                s1 = mfma32(s1, aL2[3 + m], bB);
                s2 = mfma32(s2, aL2[6 + m], bC);
            }
            fx16 acc = s0 + s1 + s2;
            store32(l2b, 1 + cl, chf, h, acc);
        }
        __syncthreads();

        // ---- P3: L3 over 32 cols (waves 0,1) + carry L1 halo (wave0)
        //         + stage next input chunk (waves 2,3) into the same buffer
        //           (safe: P1 was this chunk's only reader, two barriers ago)
        if (w < 2) {
            const int cl = l31;
            const int rb = 2 * cl;
            fx16 s0 = bias16(bias + 96, w, h);
            fx16 s1 = zero16(), s2 = zero16();
            #pragma unroll
            for (int m = 0; m < 3; m++) {
                short8 bA = *(const short8*)(l2b + swz(rb + 0, 2 * m + h));
                short8 bB = *(const short8*)(l2b + swz(rb + 1, 2 * m + h));
                short8 bC = *(const short8*)(l2b + swz(rb + 2, 2 * m + h));
                s0 = mfma32(s0, aL3[0 + m], bA);
                s1 = mfma32(s1, aL3[3 + m], bB);
                s2 = mfma32(s2, aL3[6 + m], bC);
            }
            fx16 acc = s0 + s1 + s2;
            store32(l3b, 1 + 32 * k + cl, w, h, acc);
            if (tid < 32)
                *(uint_t*)(l1b + tid * 4) = *(const uint_t*)(l1b + 128 * 128 + tid * 4);
        } else if (k < 7) {
            const int base_x = 256 * (k + 1) - 1;
            for (int ri = tid - 128; ri < INROWS; ri += 128) {
                int x = base_x + ri;
                uint_t p0 = 0, p1 = 0;
                if (x < 2048) {
                    float f0 = ldx(sig, sbase + x, mode);
                    float f1 = ldx(sig, sbase + 2048 + x, mode);
                    float f2 = ldx(sig, sbase + 4096 + x, mode);
                    float f3 = ldx(sig, sbase + 6144 + x, mode);
                    p0 = pkbf(f0, f1); p1 = pkbf(f2, f3);
                }
                uint4 vv; vv.x = p0; vv.y = p1; vv.z = 0; vv.w = 0;
                *(uint4*)(inb + ri * 16) = vv;
            }
        }
        __syncthreads();
    }

    // ---- L4: 128 cols from L3 (each wave 2 units), writes L4buf (= L1 region)
    {
        short8 a4[9];
        #pragma unroll
        for (int f = 0; f < 9; f++) a4[f] = wf[((4 + chf) * 9 + f) * 64 + lane];
        char* l4b = lds + O_L4;
        if (tid < 32) *(uint_t*)(l4b + tid * 4) = 0;  // zero halo row
        #pragma unroll
        for (int u = 0; u < 2; u++) {
            const int ct = (w >> 1) + 2 * u;
            const int cl = ct * 32 + l31;
            const int rb = 2 * cl;
            fx16 s0 = bias16(bias + 144, chf, h);
            fx16 s1 = zero16(), s2 = zero16();
            #pragma unroll
            for (int m = 0; m < 3; m++) {
                short8 bA = *(const short8*)(l3b + swz(rb + 0, 2 * m + h));
                short8 bB = *(const short8*)(l3b + swz(rb + 1, 2 * m + h));
                short8 bC = *(const short8*)(l3b + swz(rb + 2, 2 * m + h));
                s0 = mfma32(s0, a4[0 + m], bA);
                s1 = mfma32(s1, a4[3 + m], bB);
                s2 = mfma32(s2, a4[6 + m], bC);
            }
            fx16 acc = s0 + s1 + s2;
            store32(l4b, 1 + cl, chf, h, acc);
        }
    }
    __syncthreads();

    // ---- L5: 64 cols from L4, ReLU, mean over cols -> partial[s*48+co]
    {
        short8 a5[9];
        #pragma unroll
        for (int f = 0; f < 9; f++) a5[f] = wf[((6 + chf) * 9 + f) * 64 + lane];
        const char* l4b = lds + O_L4;
        float* sums = (float*)(lds + O_SUM);  // [2][48]
        const int ct = w >> 1;
        const int cl = ct * 32 + l31;
        const int rb = 2 * cl;
        fx16 s0 = bias16(bias + 192, chf, h);
        fx16 s1 = zero16(), s2 = zero16();
        #pragma unroll
        for (int m = 0; m < 3; m++) {
            short8 bA = *(const short8*)(l4b + swz(rb + 0, 2 * m + h));
            short8 bB = *(const short8*)(l4b + swz(rb + 1, 2 * m + h));
            short8 bC = *(const short8*)(l4b + swz(rb + 2, 2 * m + h));
            s0 = mfma32(s0, a5[0 + m], bA);
            s1 = mfma32(s1, a5[3 + m], bB);
            s2 = mfma32(s2, a5[6 + m], bC);
        }
        fx16 acc = s0 + s1 + s2;
        #pragma unroll
        for (int i = 0; i < 16; i++) {
            float v = fmaxf(acc[i], 0.f);
            v += __shfl_xor(v, 1, 64);
            v += __shfl_xor(v, 2, 64);
            v += __shfl_xor(v, 4, 64);
            v += __shfl_xor(v, 8, 64);
            v += __shfl_xor(v, 16, 64);
            acc[i] = v;
        }
        if (l31 == 0) {
            #pragma unroll
            for (int i = 0; i < 16; i++) {
                int co = 32 * chf + 8 * (i >> 2) + 4 * h + (i & 3);
                if (co < 45) sums[ct * 48 + co] = acc[i];
            }
        }
    }
    __syncthreads();
    if (tid < 45) {
        const float* sums = (const float*)(lds + O_SUM);
        partial[s * 48 + tid] = (sums[tid] + sums[48 + tid]) * (1.f / 64.f);
    }
}

// ---------------------------------------------------------------------------
// Per-timestep: BN1(feats over B) + Linear(64->5); concat conved(45);
// Linear(50->10) + BN2(over B) + SiLU. One block per t, 64 threads (= B).
// ---------------------------------------------------------------------------
__global__ __launch_bounds__(64) void combiner_kernel(
    const void* feats, const void* bn1_g, const void* bn1_b,
    const void* fe_w, const void* fe_b, const void* comb_w, const void* comb_b,
    const void* bn2_g, const void* bn2_b, const int* mode_p,
    const float* partial, float* z)
{
    __shared__ float sf[64 * 65];
    __shared__ float s1[64], bb1[64];
    __shared__ float fw[320], cw[500];
    __shared__ float zs[640];
    __shared__ float st2[10], bt2[10];
    const int t = blockIdx.x, tid = threadIdx.x;
    const int mode = *mode_p;

    for (int idx = tid; idx < 4096; idx += 64) {
        int b = idx >> 6, f = idx & 63;
        sf[b * 65 + f] = ldx(feats, (long)t * 4096 + idx, mode);
    }
    for (int idx = tid; idx < 320; idx += 64) fw[idx] = ldx(fe_w, idx, mode);
    for (int idx = tid; idx < 500; idx += 64) cw[idx] = ldx(comb_w, idx, mode);
    __syncthreads();
    {   // per-feature batch stats over B=64 (biased var, eps=1e-5)
        const int f = tid;
        float m = 0.f, q = 0.f;
        for (int b = 0; b < 64; b++) { float x = sf[b * 65 + f]; m += x; q += x * x; }
        m *= (1.f / 64.f); q = q * (1.f / 64.f) - m * m;
        float sc = ldx(bn1_g, f, mode) * rsqrtf(q + 1e-5f);
        s1[f] = sc; bb1[f] = ldx(bn1_b, f, mode) - m * sc;
    }
    __syncthreads();
    const int b = tid;
    float fe[5];
    #pragma unroll
    for (int o = 0; o < 5; o++) fe[o] = ldx(fe_b, o, mode);
    for (int f = 0; f < 64; f++) {
        float x = sf[b * 65 + f] * s1[f] + bb1[f];
        #pragma unroll
        for (int o = 0; o < 5; o++) fe[o] += x * fw[o * 64 + f];
    }
    float zv[10];
    #pragma unroll
    for (int o = 0; o < 10; o++) zv[o] = ldx(comb_b, o, mode);
    const float* ps = partial + (t * 64 + b) * 48;
    for (int co = 0; co < 45; co++) {
        float cv = ps[co];
        #pragma unroll
        for (int o = 0; o < 10; o++) zv[o] += cv * cw[o * 50 + co];
    }
    #pragma unroll
    for (int o5 = 0; o5 < 5; o5++) {
        #pragma unroll
        for (int o = 0; o < 10; o++) zv[o] += fe[o5] * cw[o * 50 + 45 + o5];
    }
    #pragma unroll
    for (int o = 0; o < 10; o++) zs[o * 64 + b] = zv[o];
    __syncthreads();
    if (tid < 10) {
        const int o = tid; float m = 0.f, q = 0.f;
        for (int bb = 0; bb < 64; bb++) { float x = zs[o * 64 + bb]; m += x; q += x * x; }
        m *= (1.f / 64.f); q = q * (1.f / 64.f) - m * m;
        float sc = ldx(bn2_g, o, mode) * rsqrtf(q + 1e-5f);
        st2[o] = sc; bt2[o] = ldx(bn2_b, o, mode) - m * sc;
    }
    __syncthreads();
    #pragma unroll
    for (int o = 0; o < 10; o++) {
        float x = zv[o] * st2[o] + bt2[o];
        z[t * 640 + b * 10 + o] = x / (1.f + __expf(-x));  // SiLU
    }
}

// ---------------------------------------------------------------------------
// LSTM(10, hidden 3, proj 1), sequential T=128. One block, thread = batch elem.
// ---------------------------------------------------------------------------
__global__ __launch_bounds__(64) void lstm_kernel(
    const void* w_ih, const void* w_hh, const void* b_ih, const void* b_hh,
    const void* w_hr, const int* mode_p, const float* z, float* out)
{
    __shared__ float wih[120], whh[12], bsum[12], whr[3];
    const int tid = threadIdx.x;
    const int mode = *mode_p;
    for (int i = tid; i < 120; i += 64) wih[i] = ldx(w_ih, i, mode);
    if (tid < 12) { whh[tid] = ldx(w_hh, tid, mode); bsum[tid] = ldx(b_ih, tid, mode) + ldx(b_hh, tid, mode); }
    if (tid < 3)  whr[tid] = ldx(w_hr, tid, mode);
    __syncthreads();

    const int b = tid;
    float h = 0.f, c[3] = {0.f, 0.f, 0.f};
    for (int t = 0; t < 128; t++) {
        float x[10];
        #pragma unroll
        for (int j = 0; j < 10; j++) x[j] = z[t * 640 + b * 10 + j];
        float g[12];
        #pragma unroll
        for (int i = 0; i < 12; i++) {
            float a = bsum[i] + whh[i] * h;
            #pragma unroll
            for (int j = 0; j < 10; j++) a += wih[i * 10 + j] * x[j];
            g[i] = a;
        }
        float hv = 0.f;
        #pragma unroll
        for (int d = 0; d < 3; d++) {
            float fi = 1.f / (1.f + __expf(-g[3 + d]));
            float ii = 1.f / (1.f + __expf(-g[d]));
            float gg = tanhf(g[6 + d]);
            c[d] = fi * c[d] + ii * gg;
            float oo = 1.f / (1.f + __expf(-g[9 + d]));
            hv += whr[d] * (oo * tanhf(c[d]));
        }
        h = hv;
        out[t * 64 + b] = h;
    }
}

extern "C" void kernel_launch(void* const* d_in, const int* in_sizes, int n_in,
                              void* d_out, int out_size, void* d_ws, size_t ws_size,
                              hipStream_t stream)
{
    const void* signals = d_in[0];
    const void* feats   = d_in[1];
    const void* cw0 = d_in[2];  const void* cb0 = d_in[3];
    const void* cw1 = d_in[4];  const void* cb1 = d_in[5];
    const void* cw2 = d_in[6];  const void* cb2 = d_in[7];
    const void* cw3 = d_in[8];  const void* cb3 = d_in[9];
    const void* cw4 = d_in[10]; const void* cb4 = d_in[11];
    const void* bn1_g = d_in[12]; const void* bn1_b = d_in[13];
    const void* fe_w  = d_in[14]; const void* fe_b  = d_in[15];
    const void* comb_w = d_in[16]; const void* comb_b = d_in[17];
    const void* bn2_g = d_in[18]; const void* bn2_b = d_in[19];
    const void* w_ih = d_in[20]; const void* w_hh = d_in[21];
    const void* b_ih = d_in[22]; const void* b_hh = d_in[23];
    const void* w_hr = d_in[24];

    float* ws      = (float*)d_ws;
    float* wt      = ws;
    int*   mode_p  = (int*)(ws + OFF_MODE);
    float* partial = ws + OFF_PART;
    float* z       = ws + OFF_Z;

    prep_kernel<<<1, 256, 0, stream>>>(signals, cw0, cb0, cw1, cb1, cw2, cb2,
                                       cw3, cb3, cw4, cb4, wt, mode_p);
    conv_kernel<<<8192, 256, 0, stream>>>(signals, wt, mode_p, partial);
    combiner_kernel<<<128, 64, 0, stream>>>(feats, bn1_g, bn1_b, fe_w, fe_b,
                                            comb_w, comb_b, bn2_g, bn2_b, mode_p, partial, z);
    lstm_kernel<<<1, 64, 0, stream>>>(w_ih, w_hh, b_ih, b_hh, w_hr, mode_p, z, (float*)d_out);
}